// Round 7
// baseline (290.840 us; speedup 1.0000x reference)
//
#include <hip/hip_runtime.h>
#include <stdint.h>

// out[e,o] = sum_{i,h} A[e,i,h] * W[h,i,o],  A[e] = rbf[e] @ sph[e] @ m2[e]
// Fused. chunk c = (hw = c>>6 in 0..3, i = c&63), K=32 per chunk; period = 2 chunks.
//   prolog: stage sph -> LDS (swz); rs[e,i,k] = sum_s rbf[e,i,s] sph[e,s,k] -> regs -> LDS bf16
//   per period: PRODUCE 2 A-chunks (VALU f32x4, m2 slice in regs) -> LDS quad-buf
//               8 MFMA/wave (2x4 wave grid, 32x32 tiles); W via asm global_load, in-place
//               register reuse, counted vmcnt(2); ONE barrier per period.

#define EMB 128
#define INTERM 64
#define SPH_N 16
#define KMAX 8
#define OUTD 128
#define KDIM 8192
#define EB 64
#define NTHR 512
#define NCHUNK 256   // 128 periods

typedef __attribute__((ext_vector_type(8))) short bf16x8;
typedef __attribute__((ext_vector_type(4))) float f32x4;
typedef __attribute__((ext_vector_type(4))) int i32x4;

__device__ __forceinline__ unsigned short f32_to_bf16(float f) {
  union { float f; uint32_t u; } v; v.f = f;
  uint32_t r = (v.u + 0x7fffu + ((v.u >> 16) & 1u)) >> 16;
  return (unsigned short)r;
}
__device__ __forceinline__ uint32_t cvtpk_bf16(float lo, float hi) {
  uint32_t r;
  asm("v_cvt_pk_bf16_f32 %0, %1, %2" : "=v"(r) : "v"(lo), "v"(hi));
  return r;
}
__device__ __forceinline__ float bf16lo_f(uint32_t u) { return __uint_as_float(u << 16); }
__device__ __forceinline__ float bf16hi_f(uint32_t u) { return __uint_as_float(u & 0xffff0000u); }
__device__ __forceinline__ bf16x8 as_bf(f32x4 v) {
  union { f32x4 f; bf16x8 b; } u; u.f = v; return u.b;
}
__device__ __forceinline__ void gload_bv(f32x4& d, const unsigned short* sbase, uint32_t voff) {
  asm volatile("global_load_dwordx4 %0, %1, %2" : "=&v"(d) : "v"(voff), "s"(sbase));
}

__global__ void k_build_inv(const int* __restrict__ id_reduce,
                            const int* __restrict__ id_ragged,
                            int* __restrict__ inv, int nTrip, int E) {
  int t = blockIdx.x * blockDim.x + threadIdx.x;
  if (t >= nTrip) return;
  int e = id_reduce[t], k = id_ragged[t];
  if (e >= 0 && e < E && k >= 0 && k < KMAX) inv[e * KMAX + k] = t;
}

__global__ void k_w2t(const float* __restrict__ W, unsigned short* __restrict__ W2T) {
  int idx = blockIdx.x * blockDim.x + threadIdx.x;  // [0, 128*8192)
  int o = idx >> 13;
  int c = idx & (KDIM - 1);
  int h = c & 127, i = c >> 7;
  W2T[idx] = f32_to_bf16(W[(h * INTERM + i) * OUTD + o]);
}

__global__ __launch_bounds__(NTHR, 4) void k_fused(
    const float* __restrict__ rbf,   // [E][64][16]
    const float* __restrict__ sph,   // [E][16][8]
    const float* __restrict__ m,     // [nTrip][128]
    const int* __restrict__ inv,     // [Epad][8]
    const unsigned short* __restrict__ W2T,  // [128][8192]
    float* __restrict__ out, int E)
{
  __shared__ unsigned short s_rs[EB * 64 * 8];    // 64 KB  rs[e][i][k] swz
  __shared__ unsigned short s_A[2][2][EB * 32];   // 16 KB  A quad-buf swz

  int tid = threadIdx.x;
  int e0 = blockIdx.x * EB;
  int eL = tid >> 3;          // 0..63 edge-local
  int hq = tid & 7;           // h-quarter (4h) / prolog i-group
  int eg = e0 + eL;
  bool ev = (eg < E);
  int esw = eL & 7;                    // rs slot XOR
  int hsw = ((eL >> 1) & 3) << 1;      // s_A 8B-slot XOR (even -> keeps 16B pairs)

  // ================= PROLOG =================
  // phase 1: stage sph block -> LDS f32 (swizzled slots of 8 floats)
  {
    const f32x4* g4 = (const f32x4*)(sph + (size_t)e0 * 128);
    f32x4* s4 = (f32x4*)s_rs;
#pragma unroll
    for (int j = 0; j < 4; ++j) {
      int idx = tid * 4 + j;            // 0..2047
      int ee = idx >> 5, r4 = idx & 31;
      int s = r4 >> 1, kh = r4 & 1;
      f32x4 v = (f32x4){0.f, 0.f, 0.f, 0.f};
      if (e0 + ee < E) v = g4[idx];
      s4[ee * 32 + ((s ^ (ee & 3)) << 1) + kh] = v;
    }
  }
  __syncthreads();

  // phase 2: rs[i][k] for this thread's 8 i rows, held packed in regs
  uint4 rspk[8];
  {
    const f32x4* s4 = (const f32x4*)s_rs;
    const f32x4* rb4 = (const f32x4*)(rbf + (size_t)eg * 1024);
#pragma unroll
    for (int jg = 0; jg < 4; ++jg) {
      int i0 = hq * 8 + jg * 2;
      f32x4 ra[4], rb_[4];
#pragma unroll
      for (int q = 0; q < 4; ++q) {
        ra[q]  = ev ? rb4[i0 * 4 + q]     : (f32x4){0.f, 0.f, 0.f, 0.f};
        rb_[q] = ev ? rb4[i0 * 4 + 4 + q] : (f32x4){0.f, 0.f, 0.f, 0.f};
      }
      f32x4 pa0 = (f32x4){0.f,0.f,0.f,0.f}, pa1 = pa0, pb0 = pa0, pb1 = pa0;
#pragma unroll
      for (int s = 0; s < 16; ++s) {
        f32x4 sv0 = s4[eL * 32 + ((s ^ (eL & 3)) << 1)];
        f32x4 sv1 = s4[eL * 32 + ((s ^ (eL & 3)) << 1) + 1];
        float r0 = ra[s >> 2][s & 3], r1 = rb_[s >> 2][s & 3];
        pa0 += r0 * sv0; pa1 += r0 * sv1;
        pb0 += r1 * sv0; pb1 += r1 * sv1;
      }
      rspk[jg * 2] = make_uint4(
          cvtpk_bf16(pa0[0], pa0[1]), cvtpk_bf16(pa0[2], pa0[3]),
          cvtpk_bf16(pa1[0], pa1[1]), cvtpk_bf16(pa1[2], pa1[3]));
      rspk[jg * 2 + 1] = make_uint4(
          cvtpk_bf16(pb0[0], pb0[1]), cvtpk_bf16(pb0[2], pb0[3]),
          cvtpk_bf16(pb1[0], pb1[1]), cvtpk_bf16(pb1[2], pb1[3]));
    }
  }
  __syncthreads();   // all sph reads done before overwriting s_rs

  // phase 3: write rs bf16 (swizzled)
#pragma unroll
  for (int j = 0; j < 8; ++j) {
    int i = hq * 8 + j;
    *(uint4*)&s_rs[(eL << 9) + ((i ^ esw) << 3)] = rspk[j];
  }
  __syncthreads();

  // ================= MAIN =================
  int wid = tid >> 6, lane = tid & 63;
  int ew = wid >> 2, ow = wid & 3;       // 2e x 4o, wave tile 32e x 32o
  int lr = lane & 15, lg = lane >> 4;
  int r0 = ew * 32 + lr, r1 = r0 + 16;
  uint32_t voff0 = (uint32_t)(((ow * 32 + lr) * KDIM + lg * 8) * 2);
  uint32_t voff1 = voff0 + (uint32_t)(16 * KDIM * 2);

#define AF(CUR, SL, ROW) \
  (*(const bf16x8*)&s_A[CUR][SL][((ROW) << 5) + ((lg ^ (((ROW) >> 1) & 3)) << 3)])
#define RSRD(I) (*(const uint4*)&s_rs[(eL << 9) + ((((I) & 63) ^ esw) << 3)])
#define WBASE(N) (W2T + (((N) & 63) * 128 + ((N) >> 6) * 32))

  f32x4 m2r[8];
#define LOAD_M2(HW) { \
    i32x4 iv0_, iv1_; \
    const int* ip_ = inv + (size_t)eg * 8; \
    asm volatile("global_load_dwordx4 %0, %1, off" : "=&v"(iv0_) : "v"(ip_)); \
    asm volatile("global_load_dwordx4 %0, %1, off offset:16" : "=&v"(iv1_) : "v"(ip_)); \
    asm volatile("s_waitcnt vmcnt(0)" : "+v"(iv0_), "+v"(iv1_)); \
    int tk_[8] = {iv0_[0], iv0_[1], iv0_[2], iv0_[3], iv1_[0], iv1_[1], iv1_[2], iv1_[3]}; \
    f32x4 mv_[8]; \
    _Pragma("unroll") \
    for (int k_ = 0; k_ < 8; ++k_) { \
      const float* mp_ = m + (size_t)(tk_[k_] < 0 ? 0 : tk_[k_]) * EMB + (HW) * 32 + hq * 4; \
      asm volatile("global_load_dwordx4 %0, %1, off" : "=&v"(mv_[k_]) : "v"(mp_)); \
    } \
    asm volatile("s_waitcnt vmcnt(0)" \
                 : "+v"(mv_[0]), "+v"(mv_[1]), "+v"(mv_[2]), "+v"(mv_[3]), \
                   "+v"(mv_[4]), "+v"(mv_[5]), "+v"(mv_[6]), "+v"(mv_[7])); \
    _Pragma("unroll") \
    for (int k_ = 0; k_ < 8; ++k_) \
      m2r[k_] = (tk_[k_] < 0) ? (f32x4){0.f, 0.f, 0.f, 0.f} : mv_[k_]; \
  }

#define PRODUCE(RR, BUF, SL) { \
    float rf0_ = bf16lo_f((RR).x), rf1_ = bf16hi_f((RR).x); \
    float rf2_ = bf16lo_f((RR).y), rf3_ = bf16hi_f((RR).y); \
    float rf4_ = bf16lo_f((RR).z), rf5_ = bf16hi_f((RR).z); \
    float rf6_ = bf16lo_f((RR).w), rf7_ = bf16hi_f((RR).w); \
    f32x4 ac_ = rf0_ * m2r[0]; \
    ac_ += rf1_ * m2r[1]; ac_ += rf2_ * m2r[2]; ac_ += rf3_ * m2r[3]; \
    ac_ += rf4_ * m2r[4]; ac_ += rf5_ * m2r[5]; ac_ += rf6_ * m2r[6]; \
    ac_ += rf7_ * m2r[7]; \
    uint2 pk_ = make_uint2(cvtpk_bf16(ac_[0], ac_[1]), cvtpk_bf16(ac_[2], ac_[3])); \
    *(uint2*)&s_A[BUF][SL][(eL << 5) + ((hq ^ hsw) << 2)] = pk_; \
  }

  f32x4 acc00 = (f32x4){0.f,0.f,0.f,0.f}, acc01 = acc00, acc10 = acc00, acc11 = acc00;
  f32x4 bv00, bv01, bv10, bv11;
  uint4 rsA0, rsA1, rsB0, rsB1;

  // fill: m2(hw0), A-chunks 0,1; rs(2),(3); bv(0),(1)
  LOAD_M2(0)
  {
    uint4 t0 = RSRD(0), t1 = RSRD(1);
    PRODUCE(t0, 0, 0)
    PRODUCE(t1, 0, 1)
  }
  rsA0 = RSRD(2); rsA1 = RSRD(3);
  gload_bv(bv00, WBASE(0), voff0); gload_bv(bv01, WBASE(0), voff1);
  gload_bv(bv10, WBASE(1), voff0); gload_bv(bv11, WBASE(1), voff1);
  asm volatile("s_waitcnt lgkmcnt(0)" ::: "memory");
  __builtin_amdgcn_s_barrier();

#define PERIOD(P_, CUR, RSP0, RSP1, RSN0, RSN1, M2OK, PROD, PF, W1S, W2S) { \
    const int c0_ = 2 * (P_); \
    bf16x8 a0e0 = AF(CUR, 0, r0), a0e1 = AF(CUR, 0, r1); \
    bf16x8 a1e0 = AF(CUR, 1, r0), a1e1 = AF(CUR, 1, r1); \
    RSN0 = RSRD(c0_ + 4); RSN1 = RSRD(c0_ + 5); \
    if (M2OK && (((c0_ + 2) & 63) == 0)) LOAD_M2((c0_ + 2) >> 6) \
    if (PROD) { PRODUCE(RSP0, (CUR) ^ 1, 0) PRODUCE(RSP1, (CUR) ^ 1, 1) } \
    asm volatile(W1S : "+v"(bv00), "+v"(bv01)); \
    { bf16x8 b0_ = as_bf(bv00), b1_ = as_bf(bv01); \
      acc00 = __builtin_amdgcn_mfma_f32_16x16x32_bf16(a0e0, b0_, acc00, 0, 0, 0); \
      acc01 = __builtin_amdgcn_mfma_f32_16x16x32_bf16(a0e0, b1_, acc01, 0, 0, 0); \
      acc10 = __builtin_amdgcn_mfma_f32_16x16x32_bf16(a0e1, b0_, acc10, 0, 0, 0); \
      acc11 = __builtin_amdgcn_mfma_f32_16x16x32_bf16(a0e1, b1_, acc11, 0, 0, 0); } \
    if (PF) { gload_bv(bv00, WBASE(c0_ + 2), voff0); \
              gload_bv(bv01, WBASE(c0_ + 2), voff1); } \
    asm volatile(W2S : "+v"(bv10), "+v"(bv11)); \
    { bf16x8 b0_ = as_bf(bv10), b1_ = as_bf(bv11); \
      acc00 = __builtin_amdgcn_mfma_f32_16x16x32_bf16(a1e0, b0_, acc00, 0, 0, 0); \
      acc01 = __builtin_amdgcn_mfma_f32_16x16x32_bf16(a1e0, b1_, acc01, 0, 0, 0); \
      acc10 = __builtin_amdgcn_mfma_f32_16x16x32_bf16(a1e1, b0_, acc10, 0, 0, 0); \
      acc11 = __builtin_amdgcn_mfma_f32_16x16x32_bf16(a1e1, b1_, acc11, 0, 0, 0); } \
    if (PF) { gload_bv(bv10, WBASE(c0_ + 3), voff0); \
              gload_bv(bv11, WBASE(c0_ + 3), voff1); } \
    asm volatile("s_waitcnt lgkmcnt(0)" ::: "memory"); \
    __builtin_amdgcn_s_barrier(); \
  }

  for (int p = 0; p < 126; p += 2) {
    PERIOD(p,     0, rsA0, rsA1, rsB0, rsB1, 1, 1, 1,
           "s_waitcnt vmcnt(2)", "s_waitcnt vmcnt(2)")
    PERIOD(p + 1, 1, rsB0, rsB1, rsA0, rsA1, 1, 1, 1,
           "s_waitcnt vmcnt(2)", "s_waitcnt vmcnt(2)")
  }
  PERIOD(126, 0, rsA0, rsA1, rsB0, rsB1, 0, 1, 1,
         "s_waitcnt vmcnt(2)", "s_waitcnt vmcnt(2)")
  PERIOD(127, 1, rsB0, rsB1, rsA0, rsA1, 0, 0, 0,
         "s_waitcnt vmcnt(2)", "s_waitcnt vmcnt(0)")

  // epilogue: C/D layout col = lane&15 (o), row = (lane>>4)*4 + reg (e)
  {
    int col0 = ow * 32 + lr, col1 = col0 + 16;
    int rbase = e0 + ew * 32 + lg * 4;
#pragma unroll
    for (int r = 0; r < 4; ++r) {
      int rA = rbase + r, rB = rbase + 16 + r;
      if (rA < E) {
        out[(size_t)rA * OUTD + col0] = acc00[r];
        out[(size_t)rA * OUTD + col1] = acc01[r];
      }
      if (rB < E) {
        out[(size_t)rB * OUTD + col0] = acc10[r];
        out[(size_t)rB * OUTD + col1] = acc11[r];
      }
    }
  }
}

extern "C" void kernel_launch(void* const* d_in, const int* in_sizes, int n_in,
                              void* d_out, int out_size, void* d_ws, size_t ws_size,
                              hipStream_t stream) {
  const float* rbf = (const float*)d_in[0];
  const float* sph = (const float*)d_in[1];
  const float* m   = (const float*)d_in[2];
  const float* W   = (const float*)d_in[3];
  const int* id_reduce = (const int*)d_in[4];
  const int* id_ragged = (const int*)d_in[5];
  float* out = (float*)d_out;

  int E = in_sizes[0] / (INTERM * SPH_N);   // 30000
  int nTrip = in_sizes[2] / EMB;            // 240000
  int nblk = (E + EB - 1) / EB;             // 469
  int Epad = nblk * EB;                     // 30016

  char* ws = (char*)d_ws;
  int* inv = (int*)ws;                                       // [0, 1 MB)
  unsigned short* W2T = (unsigned short*)(ws + (1u << 20));  // [1, 3 MB)

  hipMemsetAsync(inv, 0xFF, (size_t)Epad * KMAX * sizeof(int), stream);
  k_build_inv<<<(nTrip + 255) / 256, 256, 0, stream>>>(id_reduce, id_ragged, inv, nTrip, E);
  k_w2t<<<(OUTD * KDIM) / 256, 256, 0, stream>>>(W, W2T);

  k_fused<<<nblk, NTHR, 0, stream>>>(rbf, sph, m, inv, W2T, out, E);
}